// Round 3
// baseline (24270.425 us; speedup 1.0000x reference)
//
#include <hip/hip_runtime.h>
#include <hip/hip_bf16.h>

// Problem dims
#define B_   64
#define S_   256
#define E_   512
#define H_   1024
#define D_   512
#define C_   2
#define G4   4096   // 4*H
#define KIN  1536   // E+H

__device__ __forceinline__ float bf2f(unsigned short u) {
    unsigned int x = ((unsigned int)u) << 16;
    return __uint_as_float(x);
}
__device__ __forceinline__ unsigned short f2bf(float f) {
    unsigned int x = __float_as_uint(f);
    unsigned int r = (x + 0x7fffu + ((x >> 16) & 1u)) >> 16;
    return (unsigned short)r;
}

// ---------------------------------------------------------------------------
// Kernel D: detect whether float inputs are fp32 (flag=1) or bf16 (flag=0).
// Probes first 2048 uint16s of emb_table interpreted as bf16. True-bf16 data
// (N(0, 1/sqrt(512))) never exceeds |v|>4 nor lands in (0,1e-20); fp32 data's
// low mantissa halves decode to random exponents -> ~60% insane.
__global__ void detect_kernel(const unsigned short* __restrict__ emb_u,
                              int* __restrict__ flag)
{
    __shared__ int cnt;
    if (threadIdx.x == 0) cnt = 0;
    __syncthreads();
    int bad = 0;
#pragma unroll
    for (int i = 0; i < 8; ++i) {
        unsigned short u = emb_u[threadIdx.x * 8 + i];
        float a = fabsf(bf2f(u));
        if (!(a < 4.0f)) bad = 1;                     // huge or NaN
        else if (a != 0.0f && a < 1e-20f) bad = 1;    // absurdly tiny
    }
    if (bad) atomicAdd(&cnt, 1);
    __syncthreads();
    if (threadIdx.x == 0) *flag = (cnt > 16) ? 1 : 0;
}

// ---------------------------------------------------------------------------
// Kernel P: convert weights -> fp32 workspace (dtype per flag), zero h/c/fh.
// Segments: Wf 6291456 | bias 4096 | Wd 524288 | db 512 | Wp 1024 | pb 2 |
//           hA 65536 | cT 65536 | fhT 65536
#define PREP_TOTAL 7017986
__global__ void prep_kernel(const void* __restrict__ lk,
                            const void* __restrict__ lb,
                            const void* __restrict__ dw,
                            const void* __restrict__ dbm,
                            const void* __restrict__ pw,
                            const void* __restrict__ pbm,
                            const int* __restrict__ flag,
                            float* Wf, float* biasf, float* Wdf, float* dbf,
                            float* Wpf, float* pbf, float* hA, float* cT,
                            float* fhT)
{
    const bool f32 = (*flag != 0);
    long i = (long)blockIdx.x * 256 + threadIdx.x;
    if (i >= PREP_TOTAL) return;
#define CV(p, j) (f32 ? ((const float*)(p))[j] : bf2f(((const unsigned short*)(p))[j]))
    if (i < 6291456) { Wf[i]   = CV(lk, i);  return; }  i -= 6291456;
    if (i < 4096)    { biasf[i]= CV(lb, i);  return; }  i -= 4096;
    if (i < 524288)  { Wdf[i]  = CV(dw, i);  return; }  i -= 524288;
    if (i < 512)     { dbf[i]  = CV(dbm, i); return; }  i -= 512;
    if (i < 1024)    { Wpf[i]  = CV(pw, i);  return; }  i -= 1024;
    if (i < 2)       { pbf[i]  = CV(pbm, i); return; }  i -= 2;
    if (i < 65536)   { hA[i]   = 0.f;        return; }  i -= 65536;
    if (i < 65536)   { cT[i]   = 0.f;        return; }  i -= 65536;
    if (i < 65536)   { fhT[i]  = 0.f;        return; }
#undef CV
}

// ---------------------------------------------------------------------------
// Kernel A: xprojT[t][n][b] = sum_e emb[X[b,t]][e] * Wf[e][n] + bias[n]
// grid: (64 colblocks, 256 t), block 256. Wave w -> 16 cols; lane = b.
__global__ __launch_bounds__(256) void xproj_kernel(
    const int* __restrict__ X,
    const void* __restrict__ emb,
    const int* __restrict__ flag,
    const float* __restrict__ Wf,
    const float* __restrict__ biasf,
    float* __restrict__ xprojT)
{
    const int t    = blockIdx.y;
    const int cb   = blockIdx.x;
    const int tid  = threadIdx.x;
    const int lane = tid & 63;
    const int wv   = __builtin_amdgcn_readfirstlane(tid >> 6);   // 0..3
    const bool f32 = (*flag != 0);

    __shared__ float embT[128 * 64];   // [k_local][b]
    __shared__ int   rowid[64];

    if (tid < 64) rowid[tid] = X[tid * S_ + t];
    __syncthreads();

    const int n0 = cb * 64 + wv * 16;
    float acc[16];
#pragma unroll
    for (int c = 0; c < 16; ++c) acc[c] = biasf[n0 + c];

    const long myrow = (long)rowid[lane] * E_;

    for (int kc = 0; kc < 4; ++kc) {
        const int k0 = kc * 128;
        // gather+transpose: wave wv stages k in [k0 + wv*32, +32) for all b(=lane)
        if (f32) {
            const float4* src = (const float4*)((const float*)emb + myrow + k0 + wv * 32);
#pragma unroll
            for (int u = 0; u < 8; ++u) {
                float4 v = src[u];
                int kl = wv * 32 + u * 4;
                embT[(kl + 0) * 64 + lane] = v.x;
                embT[(kl + 1) * 64 + lane] = v.y;
                embT[(kl + 2) * 64 + lane] = v.z;
                embT[(kl + 3) * 64 + lane] = v.w;
            }
        } else {
            const uint4* src = (const uint4*)((const unsigned short*)emb + myrow + k0 + wv * 32);
#pragma unroll
            for (int u = 0; u < 4; ++u) {
                uint4 v = src[u];
                int kl = wv * 32 + u * 8;
                embT[(kl + 0) * 64 + lane] = bf2f((unsigned short)(v.x & 0xffff));
                embT[(kl + 1) * 64 + lane] = bf2f((unsigned short)(v.x >> 16));
                embT[(kl + 2) * 64 + lane] = bf2f((unsigned short)(v.y & 0xffff));
                embT[(kl + 3) * 64 + lane] = bf2f((unsigned short)(v.y >> 16));
                embT[(kl + 4) * 64 + lane] = bf2f((unsigned short)(v.z & 0xffff));
                embT[(kl + 5) * 64 + lane] = bf2f((unsigned short)(v.z >> 16));
                embT[(kl + 6) * 64 + lane] = bf2f((unsigned short)(v.w & 0xffff));
                embT[(kl + 7) * 64 + lane] = bf2f((unsigned short)(v.w >> 16));
            }
        }
        __syncthreads();

        const float* wbase = Wf + (long)k0 * G4 + n0;
#pragma unroll 2
        for (int k = 0; k < 128; ++k) {
            float hv = embT[k * 64 + lane];
            const float* wr = wbase + (long)k * G4;
#pragma unroll
            for (int c = 0; c < 16; ++c) acc[c] += wr[c] * hv;
        }
        __syncthreads();
    }

    float* dst = xprojT + ((long)t * G4 + n0) * 64 + lane;
#pragma unroll
    for (int c = 0; c < 16; ++c) dst[c * 64] = acc[c];
}

// ---------------------------------------------------------------------------
// Kernel B (per timestep): gates = xproj[t] + h_prev @ Wh ; pointwise update.
// grid 256 blocks x 256 thr. Block bk owns h-dims j0=bk*4..+3.
// Wave w computes gate w for those 4 j (cols n = w*1024 + j0 + c). lane = b.
__global__ __launch_bounds__(256) void lstm_step_kernel(
    const float* __restrict__ hprev, float* __restrict__ hnext,
    float* __restrict__ cT, float* __restrict__ fhT,
    const float* __restrict__ Wf, const float* __restrict__ xprojT,
    const int* __restrict__ seqlen, int t)
{
    const int tid  = threadIdx.x;
    const int lane = tid & 63;
    const int wv   = __builtin_amdgcn_readfirstlane(tid >> 6);
    const int bk   = blockIdx.x;
    const int j0   = bk * 4;
    const int n0   = wv * H_ + j0;

    __shared__ float hs[128 * 64];      // h chunk [k_local][b]  (32 KB)
    __shared__ float gx[4][4][64];      // gate exchange [gate][c][b]

    float acc[4];
    const float* xp = xprojT + ((long)t * G4 + n0) * 64 + lane;
#pragma unroll
    for (int c = 0; c < 4; ++c) acc[c] = xp[c * 64];

    for (int kc = 0; kc < 8; ++kc) {
        // stage 128x64 chunk of h_prev (linear copy, coalesced float4)
        const float4* src = (const float4*)(hprev + kc * 128 * 64);
        float4* dst = (float4*)hs;
#pragma unroll
        for (int i = 0; i < 8; ++i) dst[tid + i * 256] = src[tid + i * 256];
        __syncthreads();

        const float* wbase = Wf + (long)(E_ + kc * 128) * G4 + n0;
#pragma unroll 4
        for (int k = 0; k < 128; ++k) {
            float hv = hs[k * 64 + lane];
            const float* wr = wbase + (long)k * G4;
            acc[0] += wr[0] * hv;
            acc[1] += wr[1] * hv;
            acc[2] += wr[2] * hv;
            acc[3] += wr[3] * hv;
        }
        __syncthreads();
    }

#pragma unroll
    for (int c = 0; c < 4; ++c) gx[wv][c][lane] = acc[c];
    __syncthreads();

    // wave wv handles h-dim j = j0 + wv
    const float gi = gx[0][wv][lane];
    const float gj = gx[1][wv][lane];
    const float gf = gx[2][wv][lane];
    const float go = gx[3][wv][lane];
    const int j = j0 + wv;

    const float c_old = cT[j * 64 + lane];
    const float fgate = 1.f / (1.f + expf(-(gf + 1.0f)));   // forget bias 1.0
    const float igate = 1.f / (1.f + expf(-gi));
    const float ogate = 1.f / (1.f + expf(-go));
    const float cnew  = c_old * fgate + igate * tanhf(gj);
    const float hnew  = tanhf(cnew) * ogate;

    cT[j * 64 + lane]    = cnew;
    hnext[j * 64 + lane] = hnew;
    if (t == seqlen[lane] - 1) fhT[j * 64 + lane] = hnew;
}

// ---------------------------------------------------------------------------
// Kernel C1: denseT[d][b] = relu(fh[b] . dense_w[:,d] + db[d])
// grid 32 blocks x 256. Wave w -> 4 d-cols; lane = b.
__global__ __launch_bounds__(256) void dense_kernel(
    const float* __restrict__ fhT, const float* __restrict__ Wdf,
    const float* __restrict__ dbf, float* __restrict__ denseT)
{
    const int tid  = threadIdx.x;
    const int lane = tid & 63;
    const int wv   = __builtin_amdgcn_readfirstlane(tid >> 6);
    const int d0   = blockIdx.x * 16 + wv * 4;

    float acc[4] = {0.f, 0.f, 0.f, 0.f};
#pragma unroll 4
    for (int k = 0; k < H_; ++k) {
        float v = fhT[k * 64 + lane];
        const float* wr = Wdf + (long)k * D_ + d0;
        acc[0] += wr[0] * v;
        acc[1] += wr[1] * v;
        acc[2] += wr[2] * v;
        acc[3] += wr[3] * v;
    }
#pragma unroll
    for (int c = 0; c < 4; ++c) {
        float z = acc[c] + dbf[d0 + c];
        z = z > 0.f ? z : 0.f;
        denseT[(d0 + c) * 64 + lane] = z;
    }
}

// Kernel C2: logits[b][c] = dense[b] . pred_w[:,c] + pb[c]
// Output dtype follows the detected input dtype: fp32 when flag=1, bf16 else.
__global__ void logits_kernel(const float* __restrict__ denseT,
                              const float* __restrict__ Wpf,
                              const float* __restrict__ pbf,
                              const int* __restrict__ flag,
                              void* __restrict__ out)
{
    const int tid  = threadIdx.x;      // 128 threads: 2 waves
    const int lane = tid & 63;
    const int c    = __builtin_amdgcn_readfirstlane(tid >> 6);
    float acc = 0.f;
#pragma unroll 4
    for (int k = 0; k < D_; ++k)
        acc += denseT[k * 64 + lane] * Wpf[k * C_ + c];
    const float r = acc + pbf[c];
    if (*flag != 0) ((float*)out)[lane * C_ + c] = r;
    else            ((unsigned short*)out)[lane * C_ + c] = f2bf(r);
}

// ---------------------------------------------------------------------------
extern "C" void kernel_launch(void* const* d_in, const int* in_sizes, int n_in,
                              void* d_out, int out_size, void* d_ws, size_t ws_size,
                              hipStream_t stream)
{
    // Defensive: map inputs by their (unique) flat element counts; fall back
    // to positional (= setup_inputs dict order) if signature doesn't match.
    const int want[9] = {16384, 64, 25600000, 6291456, 4096, 524288, 512, 1024, 2};
    const void* p[9];
    for (int i = 0; i < 9; ++i) p[i] = d_in[i];
    if (n_in == 9) {
        bool ok = true;
        const void* q[9];
        for (int i = 0; i < 9; ++i) {
            int found = -1;
            for (int j = 0; j < 9; ++j) if (in_sizes[j] == want[i]) { found = j; break; }
            if (found < 0) { ok = false; break; }
            q[i] = d_in[found];
        }
        if (ok) for (int i = 0; i < 9; ++i) p[i] = q[i];
    }
    const int*  X      = (const int*)p[0];
    const int*  seqlen = (const int*)p[1];
    const void* emb    = p[2];
    const void* lk     = p[3];
    const void* lb     = p[4];
    const void* dw     = p[5];
    const void* dbm    = p[6];
    const void* pw     = p[7];
    const void* pbm    = p[8];

    float* w      = (float*)d_ws;
    float* Wf     = w;                    // 6291456 (fp32 lstm_kernel [1536][4096])
    float* biasf  = Wf     + 6291456;     // 4096
    float* Wdf    = biasf  + 4096;        // 524288
    float* dbf    = Wdf    + 524288;      // 512
    float* Wpf    = dbf    + 512;         // 1024
    float* pbf    = Wpf    + 1024;        // 2 (padded to 16)
    float* hA     = pbf    + 16;          // 65536
    float* hB     = hA     + 65536;       // 65536
    float* cT     = hB     + 65536;       // 65536
    float* fhT    = cT     + 65536;       // 65536
    float* denseT = fhT    + 65536;       // 32768
    float* xprojT = denseT + 32768;       // 67108864 (256 MiB): [t][n][b]
    int*   flag   = (int*)(xprojT + 67108864);

    detect_kernel<<<1, 256, 0, stream>>>((const unsigned short*)emb, flag);

    prep_kernel<<<27415, 256, 0, stream>>>(lk, lb, dw, dbm, pw, pbm, flag,
                                           Wf, biasf, Wdf, dbf, Wpf, pbf,
                                           hA, cT, fhT);

    xproj_kernel<<<dim3(64, 256), 256, 0, stream>>>(X, emb, flag, Wf, biasf, xprojT);

    for (int t = 0; t < S_; ++t) {
        const float* hp = (t & 1) ? hB : hA;
        float*       hn = (t & 1) ? hA : hB;
        lstm_step_kernel<<<256, 256, 0, stream>>>(hp, hn, cT, fhT, Wf, xprojT,
                                                  seqlen, t);
    }

    dense_kernel<<<32, 256, 0, stream>>>(fhT, Wdf, dbf, denseT);
    logits_kernel<<<1, 128, 0, stream>>>(denseT, Wpf, pbf, flag, d_out);
}

// Round 5
// 17670.876 us; speedup vs baseline: 1.3735x; 1.3735x over previous
//
#include <hip/hip_runtime.h>
#include <hip/hip_bf16.h>

// Problem dims
#define B_   64
#define S_   256
#define E_   512
#define H_   1024
#define D_   512
#define C_   2
#define G4   4096   // 4*H
#define NB   256    // blocks in persistent recurrence

__device__ __forceinline__ float bf2f(unsigned short u) {
    unsigned int x = ((unsigned int)u) << 16;
    return __uint_as_float(x);
}
__device__ __forceinline__ unsigned short f2bf(float f) {
    unsigned int x = __float_as_uint(f);
    unsigned int r = (x + 0x7fffu + ((x >> 16) & 1u)) >> 16;
    return (unsigned short)r;
}

// ---------------------------------------------------------------------------
// Kernel D: detect fp32 (flag=1) vs bf16 (flag=0) float inputs (probe emb).
__global__ void detect_kernel(const unsigned short* __restrict__ emb_u,
                              int* __restrict__ flag)
{
    __shared__ int cnt;
    if (threadIdx.x == 0) cnt = 0;
    __syncthreads();
    int bad = 0;
#pragma unroll
    for (int i = 0; i < 8; ++i) {
        unsigned short u = emb_u[threadIdx.x * 8 + i];
        float a = fabsf(bf2f(u));
        if (!(a < 4.0f)) bad = 1;
        else if (a != 0.0f && a < 1e-20f) bad = 1;
    }
    if (bad) atomicAdd(&cnt, 1);
    __syncthreads();
    if (threadIdx.x == 0) *flag = (cnt > 16) ? 1 : 0;
}

// ---------------------------------------------------------------------------
// Workspace float offsets
#define OFF_WFX   0L          // 2097152  (Wx rows 0..511 of lstm_kernel, [k][n])
#define OFF_WR    2097152L    // 4194304  (Wh relayout [bk][g][k][c])
#define OFF_BIAS  6291456L    // 4096
#define OFF_WD    6295552L    // 524288
#define OFF_DB    6819840L    // 512
#define OFF_WP    6820352L    // 1024
#define OFF_PB    6821376L    // 16 (2 used)
#define OFF_HA    6821392L    // 65536
#define OFF_HB    6886928L    // 65536
#define OFF_CT    6952464L    // 65536
#define OFF_FH    7018000L    // 65536
#define OFF_DEN   7083536L    // 32768
#define OFF_BAR   7116304L    // 16 uints: [0]=cnt, [4]=gen (zeroed), [8]=flag (NOT zeroed)
#define OFF_XPROJ 7116320L    // 67108864

// Kernel P: convert/relayout weights, zero state + barrier counters ONLY.
// Items: Wfx 2097152 | Wr 4194304 | bias 4096 | Wd 524288 | db 512 | Wp 1024 |
//        pb 2 | zeros (hA 65536, cT 65536, fhT 65536, bar 8) => total 7017994
#define PREP_TOTAL 7017994
__global__ void prep_kernel(const void* __restrict__ lk,
                            const void* __restrict__ lb,
                            const void* __restrict__ dw,
                            const void* __restrict__ dbm,
                            const void* __restrict__ pw,
                            const void* __restrict__ pbm,
                            const int* __restrict__ flag,
                            float* __restrict__ w)
{
    const bool f32 = (*flag != 0);
    long i = (long)blockIdx.x * 256 + threadIdx.x;
    if (i >= PREP_TOTAL) return;
#define CV(p, j) (f32 ? ((const float*)(p))[j] : bf2f(((const unsigned short*)(p))[j]))
    if (i < 2097152) { w[OFF_WFX + i] = CV(lk, i); return; }  i -= 2097152;
    if (i < 4194304) {
        // Wr[((bk*4+g)*1024 + k)*4 + c] = Wh[k][g*1024 + bk*4 + c]
        int c  = (int)(i & 3);
        int k  = (int)((i >> 2) & 1023);
        int gg = (int)((i >> 12) & 3);
        int bk = (int)(i >> 14);
        long src = (long)(512 + k) * G4 + gg * H_ + bk * 4 + c;
        w[OFF_WR + i] = CV(lk, src); return;
    }  i -= 4194304;
    if (i < 4096)    { w[OFF_BIAS + i] = CV(lb, i);  return; }  i -= 4096;
    if (i < 524288)  { w[OFF_WD + i]   = CV(dw, i);  return; }  i -= 524288;
    if (i < 512)     { w[OFF_DB + i]   = CV(dbm, i); return; }  i -= 512;
    if (i < 1024)    { w[OFF_WP + i]   = CV(pw, i);  return; }  i -= 1024;
    if (i < 2)       { w[OFF_PB + i]   = CV(pbm, i); return; }  i -= 2;
    // zeros: hA 65536 | cT 65536 | fhT 65536 | bar counters 8 (flag untouched!)
    if (i < 65536)   { w[OFF_HA + i] = 0.f; return; }  i -= 65536;
    if (i < 65536)   { w[OFF_CT + i] = 0.f; return; }  i -= 65536;
    if (i < 65536)   { w[OFF_FH + i] = 0.f; return; }  i -= 65536;
    if (i < 8)       { ((unsigned int*)(w + OFF_BAR))[i] = 0u; return; }
#undef CV
}

// ---------------------------------------------------------------------------
// Kernel A: xprojT[t][n][b] = sum_e emb[X[b,t]][e] * Wfx[e][n] + bias[n]
__global__ __launch_bounds__(256) void xproj_kernel(
    const int* __restrict__ X,
    const void* __restrict__ emb,
    const int* __restrict__ flag,
    const float* __restrict__ Wfx,
    const float* __restrict__ biasf,
    float* __restrict__ xprojT)
{
    const int t    = blockIdx.y;
    const int cb   = blockIdx.x;
    const int tid  = threadIdx.x;
    const int lane = tid & 63;
    const int wv   = __builtin_amdgcn_readfirstlane(tid >> 6);
    const bool f32 = (*flag != 0);

    __shared__ float embT[128 * 64];
    __shared__ int   rowid[64];

    if (tid < 64) rowid[tid] = X[tid * S_ + t];
    __syncthreads();

    const int n0 = cb * 64 + wv * 16;
    float acc[16];
#pragma unroll
    for (int c = 0; c < 16; ++c) acc[c] = biasf[n0 + c];

    const long myrow = (long)rowid[lane] * E_;

    for (int kc = 0; kc < 4; ++kc) {
        const int k0 = kc * 128;
        if (f32) {
            const float4* src = (const float4*)((const float*)emb + myrow + k0 + wv * 32);
#pragma unroll
            for (int u = 0; u < 8; ++u) {
                float4 v = src[u];
                int kl = wv * 32 + u * 4;
                embT[(kl + 0) * 64 + lane] = v.x;
                embT[(kl + 1) * 64 + lane] = v.y;
                embT[(kl + 2) * 64 + lane] = v.z;
                embT[(kl + 3) * 64 + lane] = v.w;
            }
        } else {
            const uint4* src = (const uint4*)((const unsigned short*)emb + myrow + k0 + wv * 32);
#pragma unroll
            for (int u = 0; u < 4; ++u) {
                uint4 v = src[u];
                int kl = wv * 32 + u * 8;
                embT[(kl + 0) * 64 + lane] = bf2f((unsigned short)(v.x & 0xffff));
                embT[(kl + 1) * 64 + lane] = bf2f((unsigned short)(v.x >> 16));
                embT[(kl + 2) * 64 + lane] = bf2f((unsigned short)(v.y & 0xffff));
                embT[(kl + 3) * 64 + lane] = bf2f((unsigned short)(v.y >> 16));
                embT[(kl + 4) * 64 + lane] = bf2f((unsigned short)(v.z & 0xffff));
                embT[(kl + 5) * 64 + lane] = bf2f((unsigned short)(v.z >> 16));
                embT[(kl + 6) * 64 + lane] = bf2f((unsigned short)(v.w & 0xffff));
                embT[(kl + 7) * 64 + lane] = bf2f((unsigned short)(v.w >> 16));
            }
        }
        __syncthreads();

        const float* wbase = Wfx + (long)k0 * G4 + n0;
#pragma unroll 2
        for (int k = 0; k < 128; ++k) {
            float hv = embT[k * 64 + lane];
            const float* wr = wbase + (long)k * G4;
#pragma unroll
            for (int c = 0; c < 16; ++c) acc[c] += wr[c] * hv;
        }
        __syncthreads();
    }

    float* dst = xprojT + ((long)t * G4 + n0) * 64 + lane;
#pragma unroll
    for (int c = 0; c < 16; ++c) dst[c * 64] = acc[c];
}

// ---------------------------------------------------------------------------
// Device-scope sense-reversing grid barrier. Safe: 60 KB LDS/block caps
// residency at 2/CU -> capacity 512 >= NB, all blocks co-resident.
__device__ __forceinline__ void grid_barrier(unsigned int* bar)
{
    __syncthreads();
    if (threadIdx.x == 0) {
        __threadfence();   // release h stores (agent scope, wb L2)
        unsigned int* cnt = bar;
        unsigned int* gen = bar + 4;
        unsigned int g = __hip_atomic_load(gen, __ATOMIC_RELAXED, __HIP_MEMORY_SCOPE_AGENT);
        unsigned int a = __hip_atomic_fetch_add(cnt, 1u, __ATOMIC_ACQ_REL, __HIP_MEMORY_SCOPE_AGENT);
        if (a == NB - 1) {
            __hip_atomic_store(cnt, 0u, __ATOMIC_RELAXED, __HIP_MEMORY_SCOPE_AGENT);
            __hip_atomic_fetch_add(gen, 1u, __ATOMIC_RELEASE, __HIP_MEMORY_SCOPE_AGENT);
        } else {
            while (__hip_atomic_load(gen, __ATOMIC_ACQUIRE, __HIP_MEMORY_SCOPE_AGENT) == g) {
                __builtin_amdgcn_s_sleep(8);
            }
        }
        __threadfence();   // acquire: invalidate L1 so h reads are fresh
    }
    __syncthreads();
}

// ---------------------------------------------------------------------------
// Persistent LSTM recurrence. 256 blocks x 256 thr. Block bk owns h-dims
// j0..j0+3 (16 gate cols). Wave g computes gate g for 4 j's. lane = batch.
__global__ __launch_bounds__(256) void lstm_persistent(
    float* __restrict__ hA, float* __restrict__ hB,
    float* __restrict__ cT, float* __restrict__ fhT,
    const float* __restrict__ Wr, const float* __restrict__ xprojT,
    const int* __restrict__ seqlen, unsigned int* __restrict__ bar)
{
    const int tid  = threadIdx.x;
    const int lane = tid & 63;
    const int g    = __builtin_amdgcn_readfirstlane(tid >> 6);
    const int bk   = blockIdx.x;
    const int j0   = bk * 4;

    __shared__ float hs[8192];      // 32 KB  [k_local][b]
    __shared__ float gx[4][4][64];  // 4 KB
    __shared__ float pad[6144];     // pad LDS to 60 KB -> <=2 blocks/CU

    if ((unsigned long long)xprojT == 1ull) pad[tid & 4095] = 0.f; // keep pad

    // wave g's weight slice: Wr + (bk*4+g)*4096, 4 floats per k, contiguous
    const float* wbase = Wr + ((long)(bk * 4 + g) << 12);
    const int myseq = seqlen[lane];

    float* hp = hA;
    float* hn = hB;

    for (int t = 0; t < S_; ++t) {
        const float* xp = xprojT + ((long)t * G4 + g * H_ + j0) * 64 + lane;
        float acc0 = xp[0], acc1 = xp[64], acc2 = xp[128], acc3 = xp[192];

        for (int kc = 0; kc < 8; ++kc) {
            // stage 128x64 h-chunk into LDS (coalesced float4)
            {
                const float4* src = (const float4*)(hp + kc * 8192);
                float4* dst = (float4*)hs;
#pragma unroll
                for (int u = 0; u < 8; ++u)
                    dst[tid + u * 256] = src[tid + u * 256];
            }
            __syncthreads();

            const float* wk = wbase + (kc << 9);
#pragma unroll 8
            for (int k = 0; k < 128; ++k) {
                const float hv = hs[k * 64 + lane];
                const float4 w4 = *(const float4*)(wk + (k << 2));
                acc0 += w4.x * hv;
                acc1 += w4.y * hv;
                acc2 += w4.z * hv;
                acc3 += w4.w * hv;
            }
            __syncthreads();
        }

        gx[g][0][lane] = acc0;
        gx[g][1][lane] = acc1;
        gx[g][2][lane] = acc2;
        gx[g][3][lane] = acc3;
        __syncthreads();

        // wave g handles h-dim j = j0 + g  (gate order: i, j, f, o)
        const float gi = gx[0][g][lane];
        const float gj = gx[1][g][lane];
        const float gf = gx[2][g][lane];
        const float go = gx[3][g][lane];
        const int j = j0 + g;

        const float c_old = cT[j * 64 + lane];
        const float fgate = 1.f / (1.f + expf(-(gf + 1.0f)));  // forget bias
        const float igate = 1.f / (1.f + expf(-gi));
        const float ogate = 1.f / (1.f + expf(-go));
        const float cnew  = c_old * fgate + igate * tanhf(gj);
        const float hnew  = tanhf(cnew) * ogate;

        cT[j * 64 + lane] = cnew;
        hn[j * 64 + lane] = hnew;
        if (t == myseq - 1) fhT[j * 64 + lane] = hnew;

        grid_barrier(bar);

        float* tmp = hp; hp = hn; hn = tmp;
    }
}

// ---------------------------------------------------------------------------
// Kernel C1: denseT[d][b] = relu(fh[b] . dense_w[:,d] + db[d])
__global__ __launch_bounds__(256) void dense_kernel(
    const float* __restrict__ fhT, const float* __restrict__ Wdf,
    const float* __restrict__ dbf, float* __restrict__ denseT)
{
    const int tid  = threadIdx.x;
    const int lane = tid & 63;
    const int wv   = __builtin_amdgcn_readfirstlane(tid >> 6);
    const int d0   = blockIdx.x * 16 + wv * 4;

    float acc[4] = {0.f, 0.f, 0.f, 0.f};
#pragma unroll 4
    for (int k = 0; k < H_; ++k) {
        float v = fhT[k * 64 + lane];
        const float* wr = Wdf + (long)k * D_ + d0;
        acc[0] += wr[0] * v;
        acc[1] += wr[1] * v;
        acc[2] += wr[2] * v;
        acc[3] += wr[3] * v;
    }
#pragma unroll
    for (int c = 0; c < 4; ++c) {
        float z = acc[c] + dbf[d0 + c];
        z = z > 0.f ? z : 0.f;
        denseT[(d0 + c) * 64 + lane] = z;
    }
}

// Kernel C2: logits; output dtype follows detected input dtype.
__global__ void logits_kernel(const float* __restrict__ denseT,
                              const float* __restrict__ Wpf,
                              const float* __restrict__ pbf,
                              const int* __restrict__ flag,
                              void* __restrict__ out)
{
    const int tid  = threadIdx.x;      // 128 threads: 2 waves
    const int lane = tid & 63;
    const int c    = __builtin_amdgcn_readfirstlane(tid >> 6);
    float acc = 0.f;
#pragma unroll 4
    for (int k = 0; k < D_; ++k)
        acc += denseT[k * 64 + lane] * Wpf[k * C_ + c];
    const float r = acc + pbf[c];
    if (*flag != 0) ((float*)out)[lane * C_ + c] = r;
    else            ((unsigned short*)out)[lane * C_ + c] = f2bf(r);
}

// ---------------------------------------------------------------------------
extern "C" void kernel_launch(void* const* d_in, const int* in_sizes, int n_in,
                              void* d_out, int out_size, void* d_ws, size_t ws_size,
                              hipStream_t stream)
{
    // Map inputs by unique flat element counts; fall back to positional.
    const int want[9] = {16384, 64, 25600000, 6291456, 4096, 524288, 512, 1024, 2};
    const void* p[9];
    for (int i = 0; i < 9; ++i) p[i] = d_in[i];
    if (n_in == 9) {
        bool ok = true;
        const void* q[9];
        for (int i = 0; i < 9; ++i) {
            int found = -1;
            for (int j = 0; j < 9; ++j) if (in_sizes[j] == want[i]) { found = j; break; }
            if (found < 0) { ok = false; break; }
            q[i] = d_in[found];
        }
        if (ok) for (int i = 0; i < 9; ++i) p[i] = q[i];
    }
    const int*  X      = (const int*)p[0];
    const int*  seqlen = (const int*)p[1];
    const void* emb    = p[2];
    const void* lk     = p[3];
    const void* lb     = p[4];
    const void* dw     = p[5];
    const void* dbm    = p[6];
    const void* pw     = p[7];
    const void* pbm    = p[8];

    float* w = (float*)d_ws;
    unsigned int* bar  = (unsigned int*)(w + OFF_BAR);
    int*          flag = (int*)(w + OFF_BAR) + 8;   // outside zeroed range

    detect_kernel<<<1, 256, 0, stream>>>((const unsigned short*)emb, flag);

    prep_kernel<<<27415, 256, 0, stream>>>(lk, lb, dw, dbm, pw, pbm, flag, w);

    xproj_kernel<<<dim3(64, 256), 256, 0, stream>>>(X, emb, flag,
                                                    w + OFF_WFX, w + OFF_BIAS,
                                                    w + OFF_XPROJ);

    lstm_persistent<<<NB, 256, 0, stream>>>(w + OFF_HA, w + OFF_HB,
                                            w + OFF_CT, w + OFF_FH,
                                            w + OFF_WR, w + OFF_XPROJ,
                                            seqlen, bar);

    dense_kernel<<<32, 256, 0, stream>>>(w + OFF_FH, w + OFF_WD,
                                         w + OFF_DB, w + OFF_DEN);
    logits_kernel<<<1, 128, 0, stream>>>(w + OFF_DEN, w + OFF_WP,
                                         w + OFF_PB, flag, d_out);
}

// Round 6
// 11497.488 us; speedup vs baseline: 2.1109x; 1.5369x over previous
//
#include <hip/hip_runtime.h>
#include <hip/hip_bf16.h>

// Problem dims
#define B_   64
#define S_   256
#define E_   512
#define H_   1024
#define D_   512
#define C_   2
#define G4   4096   // 4*H
#define NB   256    // blocks in persistent recurrence

__device__ __forceinline__ float bf2f(unsigned short u) {
    unsigned int x = ((unsigned int)u) << 16;
    return __uint_as_float(x);
}
__device__ __forceinline__ unsigned short f2bf(float f) {
    unsigned int x = __float_as_uint(f);
    unsigned int r = (x + 0x7fffu + ((x >> 16) & 1u)) >> 16;
    return (unsigned short)r;
}

// ---------------------------------------------------------------------------
// Kernel D: detect fp32 (flag=1) vs bf16 (flag=0) float inputs (probe emb).
__global__ void detect_kernel(const unsigned short* __restrict__ emb_u,
                              int* __restrict__ flag)
{
    __shared__ int cnt;
    if (threadIdx.x == 0) cnt = 0;
    __syncthreads();
    int bad = 0;
#pragma unroll
    for (int i = 0; i < 8; ++i) {
        unsigned short u = emb_u[threadIdx.x * 8 + i];
        float a = fabsf(bf2f(u));
        if (!(a < 4.0f)) bad = 1;
        else if (a != 0.0f && a < 1e-20f) bad = 1;
    }
    if (bad) atomicAdd(&cnt, 1);
    __syncthreads();
    if (threadIdx.x == 0) *flag = (cnt > 16) ? 1 : 0;
}

// ---------------------------------------------------------------------------
// Workspace float offsets
#define OFF_WFX   0L          // 2097152  (Wx rows 0..511 of lstm_kernel, [k][n])
#define OFF_WR    2097152L    // 4194304  (Wh relayout [bk][k][c16], c=g*4+jj)
#define OFF_BIAS  6291456L    // 4096
#define OFF_WD    6295552L    // 524288
#define OFF_DB    6819840L    // 512
#define OFF_WP    6820352L    // 1024
#define OFF_PB    6821376L    // 16 (2 used)
#define OFF_HA    6821392L    // 65536
#define OFF_HB    6886928L    // 65536
#define OFF_CT    6952464L    // 65536
#define OFF_FH    7018000L    // 65536
#define OFF_DEN   7083536L    // 32768
#define OFF_BAR   7116304L    // 512 uints: subs@0..224(stride32), master@256, gen@288, flag@400
#define OFF_XPROJ 7116816L    // 67108864

// Kernel P: convert/relayout weights, zero state + barrier counters.
// Items: Wfx 2097152 | Wr 4194304 | bias 4096 | Wd 524288 | db 512 | Wp 1024 |
//        pb 2 | hA 65536 | cT 65536 | fhT 65536 | bar 320  => 7018306
#define PREP_TOTAL 7018306
__global__ void prep_kernel(const void* __restrict__ lk,
                            const void* __restrict__ lb,
                            const void* __restrict__ dw,
                            const void* __restrict__ dbm,
                            const void* __restrict__ pw,
                            const void* __restrict__ pbm,
                            const int* __restrict__ flag,
                            float* __restrict__ w)
{
    const bool f32 = (*flag != 0);
    long i = (long)blockIdx.x * 256 + threadIdx.x;
    if (i >= PREP_TOTAL) return;
#define CV(p, j) (f32 ? ((const float*)(p))[j] : bf2f(((const unsigned short*)(p))[j]))
    if (i < 2097152) { w[OFF_WFX + i] = CV(lk, i); return; }  i -= 2097152;
    if (i < 4194304) {
        // Wr[bk*16384 + k*16 + c] = Wh[k][g*1024 + bk*4 + jj], c = g*4+jj
        int c  = (int)(i & 15);
        int k  = (int)((i >> 4) & 1023);
        int bk = (int)(i >> 14);
        int g  = c >> 2;
        int jj = c & 3;
        long src = (long)(512 + k) * G4 + g * H_ + bk * 4 + jj;
        w[OFF_WR + i] = CV(lk, src); return;
    }  i -= 4194304;
    if (i < 4096)    { w[OFF_BIAS + i] = CV(lb, i);  return; }  i -= 4096;
    if (i < 524288)  { w[OFF_WD + i]   = CV(dw, i);  return; }  i -= 524288;
    if (i < 512)     { w[OFF_DB + i]   = CV(dbm, i); return; }  i -= 512;
    if (i < 1024)    { w[OFF_WP + i]   = CV(pw, i);  return; }  i -= 1024;
    if (i < 2)       { w[OFF_PB + i]   = CV(pbm, i); return; }  i -= 2;
    if (i < 65536)   { w[OFF_HA + i] = 0.f; return; }  i -= 65536;
    if (i < 65536)   { w[OFF_CT + i] = 0.f; return; }  i -= 65536;
    if (i < 65536)   { w[OFF_FH + i] = 0.f; return; }  i -= 65536;
    if (i < 320)     { ((unsigned int*)(w + OFF_BAR))[i] = 0u; return; }
#undef CV
}

// ---------------------------------------------------------------------------
// Kernel A: xprojT[t][n][b] = sum_e emb[X[b,t]][e] * Wfx[e][n] + bias[n]
__global__ __launch_bounds__(256) void xproj_kernel(
    const int* __restrict__ X,
    const void* __restrict__ emb,
    const int* __restrict__ flag,
    const float* __restrict__ Wfx,
    const float* __restrict__ biasf,
    float* __restrict__ xprojT)
{
    const int t    = blockIdx.y;
    const int cb   = blockIdx.x;
    const int tid  = threadIdx.x;
    const int lane = tid & 63;
    const int wv   = __builtin_amdgcn_readfirstlane(tid >> 6);
    const bool f32 = (*flag != 0);

    __shared__ float embT[128 * 64];
    __shared__ int   rowid[64];

    if (tid < 64) rowid[tid] = X[tid * S_ + t];
    __syncthreads();

    const int n0 = cb * 64 + wv * 16;
    float acc[16];
#pragma unroll
    for (int c = 0; c < 16; ++c) acc[c] = biasf[n0 + c];

    const long myrow = (long)rowid[lane] * E_;

    for (int kc = 0; kc < 4; ++kc) {
        const int k0 = kc * 128;
        if (f32) {
            const float4* src = (const float4*)((const float*)emb + myrow + k0 + wv * 32);
#pragma unroll
            for (int u = 0; u < 8; ++u) {
                float4 v = src[u];
                int kl = wv * 32 + u * 4;
                embT[(kl + 0) * 64 + lane] = v.x;
                embT[(kl + 1) * 64 + lane] = v.y;
                embT[(kl + 2) * 64 + lane] = v.z;
                embT[(kl + 3) * 64 + lane] = v.w;
            }
        } else {
            const uint4* src = (const uint4*)((const unsigned short*)emb + myrow + k0 + wv * 32);
#pragma unroll
            for (int u = 0; u < 4; ++u) {
                uint4 v = src[u];
                int kl = wv * 32 + u * 8;
                embT[(kl + 0) * 64 + lane] = bf2f((unsigned short)(v.x & 0xffff));
                embT[(kl + 1) * 64 + lane] = bf2f((unsigned short)(v.x >> 16));
                embT[(kl + 2) * 64 + lane] = bf2f((unsigned short)(v.y & 0xffff));
                embT[(kl + 3) * 64 + lane] = bf2f((unsigned short)(v.y >> 16));
                embT[(kl + 4) * 64 + lane] = bf2f((unsigned short)(v.z & 0xffff));
                embT[(kl + 5) * 64 + lane] = bf2f((unsigned short)(v.z >> 16));
                embT[(kl + 6) * 64 + lane] = bf2f((unsigned short)(v.w & 0xffff));
                embT[(kl + 7) * 64 + lane] = bf2f((unsigned short)(v.w >> 16));
            }
        }
        __syncthreads();

        const float* wbase = Wfx + (long)k0 * G4 + n0;
#pragma unroll 2
        for (int k = 0; k < 128; ++k) {
            float hv = embT[k * 64 + lane];
            const float* wr = wbase + (long)k * G4;
#pragma unroll
            for (int c = 0; c < 16; ++c) acc[c] += wr[c] * hv;
        }
        __syncthreads();
    }

    float* dst = xprojT + ((long)t * G4 + n0) * 64 + lane;
#pragma unroll
    for (int c = 0; c < 16; ++c) dst[c * 64] = acc[c];
}

// ---------------------------------------------------------------------------
// Hierarchical monotonic grid barrier: 8 sub-counters (by bk&7) + master.
// Monotonic targets (no resets) -> race-free across steps.
__device__ __forceinline__ void grid_barrier(unsigned int* bar, int t)
{
    __syncthreads();
    if (threadIdx.x == 0) {
        __threadfence();   // release h/c stores (agent scope)
        unsigned int* sub    = bar + ((blockIdx.x & 7) << 5);
        unsigned int* master = bar + 256;
        unsigned int* gen    = bar + 288;
        unsigned int a = __hip_atomic_fetch_add(sub, 1u, __ATOMIC_ACQ_REL, __HIP_MEMORY_SCOPE_AGENT);
        if (a == (unsigned)(t * 32 + 31)) {
            unsigned int m = __hip_atomic_fetch_add(master, 1u, __ATOMIC_ACQ_REL, __HIP_MEMORY_SCOPE_AGENT);
            if (m == (unsigned)(t * 8 + 7))
                __hip_atomic_store(gen, (unsigned)(t + 1), __ATOMIC_RELEASE, __HIP_MEMORY_SCOPE_AGENT);
        }
        while (__hip_atomic_load(gen, __ATOMIC_ACQUIRE, __HIP_MEMORY_SCOPE_AGENT) <= (unsigned)t) {
            __builtin_amdgcn_s_sleep(1);
        }
        __threadfence();   // acquire: fresh h reads next step
    }
    __syncthreads();
}

// ---------------------------------------------------------------------------
// Persistent LSTM recurrence. 256 blocks x 512 thr (8 waves).
// Block bk owns h-dims j0=bk*4..+3 (16 gate cols, c=g*4+jj).
// Wave kg computes ALL 16 cols over k-slice [kg*128, kg*128+128).
// Weights: wave-uniform rows Wr[bk][k][c16] -> scalar (SMEM) loads.
// h: direct global coalesced reads (lane=batch), 8-deep pipelined.
// LDS: only the 8-way k-partial reduction (32 KB).
__global__ __launch_bounds__(512) void lstm_persistent(
    float* __restrict__ hA, float* __restrict__ hB,
    float* __restrict__ cT, float* __restrict__ fhT,
    const float* __restrict__ Wr, const float* __restrict__ xprojT,
    const int* __restrict__ seqlen, unsigned int* __restrict__ bar)
{
    const int tid  = threadIdx.x;
    const int lane = tid & 63;
    const int wv   = __builtin_amdgcn_readfirstlane(tid >> 6);  // 0..7 = kg
    const int bk   = blockIdx.x;
    const int j0   = bk * 4;

    __shared__ float gx[8192];     // [kg][c][lane]  32 KB
    __shared__ float keep[7936];   // pad LDS to ~63 KB (anti-packing)

    // Opaque runtime guard (never true) so `keep` isn't DCE'd.
    if (seqlen[0] == -2147483647) {
        keep[tid] = (float)tid;
        __syncthreads();
        if (keep[(tid + 1) & 511] > 1e30f) fhT[0] = 0.f;
    }

    const int myseq = seqlen[lane];
    const float* wk = Wr + (long)bk * 16384 + (long)wv * 2048;  // 128 k-rows x 16

    float* hp = hA;
    float* hn = hB;

    for (int t = 0; t < S_; ++t) {
        // pointwise waves prefetch xproj for this step (consumed after syncs)
        float xq0 = 0.f, xq1 = 0.f, xq2 = 0.f, xq3 = 0.f;
        if (wv < 4) {
            const long base = (long)t * G4;
            const int  j    = j0 + wv;
            xq0 = xprojT[(base + 0 * H_ + j) * 64 + lane];
            xq1 = xprojT[(base + 1 * H_ + j) * 64 + lane];
            xq2 = xprojT[(base + 2 * H_ + j) * 64 + lane];
            xq3 = xprojT[(base + 3 * H_ + j) * 64 + lane];
        }

        const float* hk = hp + wv * (128 * 64);
        float acc[16];
#pragma unroll
        for (int c = 0; c < 16; ++c) acc[c] = 0.f;

        // k-loop: 128 k, 8 h-values in flight, W rows are uniform loads
        float hbuf[8];
#pragma unroll
        for (int u = 0; u < 8; ++u) hbuf[u] = hk[u * 64 + lane];
        for (int kb = 0; kb < 128; kb += 8) {
            float hcur[8];
#pragma unroll
            for (int u = 0; u < 8; ++u) hcur[u] = hbuf[u];
            if (kb + 8 < 128) {
#pragma unroll
                for (int u = 0; u < 8; ++u) hbuf[u] = hk[(kb + 8 + u) * 64 + lane];
            }
#pragma unroll
            for (int u = 0; u < 8; ++u) {
                const float* wrow = wk + (kb + u) * 16;
#pragma unroll
                for (int c = 0; c < 16; ++c)
                    acc[c] = fmaf(wrow[c], hcur[u], acc[c]);
            }
        }

        // partials -> LDS
#pragma unroll
        for (int c = 0; c < 16; ++c)
            gx[(wv * 16 + c) * 64 + lane] = acc[c];
        __syncthreads();

        if (wv < 4) {
            const int j = j0 + wv;
            float gi = xq0, gj = xq1, gf = xq2, go = xq3;
#pragma unroll
            for (int kg = 0; kg < 8; ++kg) {
                gi += gx[(kg * 16 + 0 * 4 + wv) * 64 + lane];
                gj += gx[(kg * 16 + 1 * 4 + wv) * 64 + lane];
                gf += gx[(kg * 16 + 2 * 4 + wv) * 64 + lane];
                go += gx[(kg * 16 + 3 * 4 + wv) * 64 + lane];
            }
            const float c_old = cT[j * 64 + lane];
            const float fgate = 1.f / (1.f + expf(-(gf + 1.0f)));  // forget bias
            const float igate = 1.f / (1.f + expf(-gi));
            const float ogate = 1.f / (1.f + expf(-go));
            const float cnew  = c_old * fgate + igate * tanhf(gj);
            const float hnew  = tanhf(cnew) * ogate;

            cT[j * 64 + lane] = cnew;
            hn[j * 64 + lane] = hnew;
            if (t == myseq - 1) fhT[j * 64 + lane] = hnew;
        }

        grid_barrier(bar, t);

        float* tmp = hp; hp = hn; hn = tmp;
    }
}

// ---------------------------------------------------------------------------
// Kernel C1: denseT[d][b] = relu(fh[b] . dense_w[:,d] + db[d])
__global__ __launch_bounds__(256) void dense_kernel(
    const float* __restrict__ fhT, const float* __restrict__ Wdf,
    const float* __restrict__ dbf, float* __restrict__ denseT)
{
    const int tid  = threadIdx.x;
    const int lane = tid & 63;
    const int wv   = __builtin_amdgcn_readfirstlane(tid >> 6);
    const int d0   = blockIdx.x * 16 + wv * 4;

    float acc[4] = {0.f, 0.f, 0.f, 0.f};
#pragma unroll 4
    for (int k = 0; k < H_; ++k) {
        float v = fhT[k * 64 + lane];
        const float* wr = Wdf + (long)k * D_ + d0;
        acc[0] += wr[0] * v;
        acc[1] += wr[1] * v;
        acc[2] += wr[2] * v;
        acc[3] += wr[3] * v;
    }
#pragma unroll
    for (int c = 0; c < 4; ++c) {
        float z = acc[c] + dbf[d0 + c];
        z = z > 0.f ? z : 0.f;
        denseT[(d0 + c) * 64 + lane] = z;
    }
}

// Kernel C2: logits; output dtype follows detected input dtype.
__global__ void logits_kernel(const float* __restrict__ denseT,
                              const float* __restrict__ Wpf,
                              const float* __restrict__ pbf,
                              const int* __restrict__ flag,
                              void* __restrict__ out)
{
    const int tid  = threadIdx.x;      // 128 threads: 2 waves
    const int lane = tid & 63;
    const int c    = __builtin_amdgcn_readfirstlane(tid >> 6);
    float acc = 0.f;
#pragma unroll 4
    for (int k = 0; k < D_; ++k)
        acc += denseT[k * 64 + lane] * Wpf[k * C_ + c];
    const float r = acc + pbf[c];
    if (*flag != 0) ((float*)out)[lane * C_ + c] = r;
    else            ((unsigned short*)out)[lane * C_ + c] = f2bf(r);
}

// ---------------------------------------------------------------------------
extern "C" void kernel_launch(void* const* d_in, const int* in_sizes, int n_in,
                              void* d_out, int out_size, void* d_ws, size_t ws_size,
                              hipStream_t stream)
{
    // Map inputs by unique flat element counts; fall back to positional.
    const int want[9] = {16384, 64, 25600000, 6291456, 4096, 524288, 512, 1024, 2};
    const void* p[9];
    for (int i = 0; i < 9; ++i) p[i] = d_in[i];
    if (n_in == 9) {
        bool ok = true;
        const void* q[9];
        for (int i = 0; i < 9; ++i) {
            int found = -1;
            for (int j = 0; j < 9; ++j) if (in_sizes[j] == want[i]) { found = j; break; }
            if (found < 0) { ok = false; break; }
            q[i] = d_in[found];
        }
        if (ok) for (int i = 0; i < 9; ++i) p[i] = q[i];
    }
    const int*  X      = (const int*)p[0];
    const int*  seqlen = (const int*)p[1];
    const void* emb    = p[2];
    const void* lk     = p[3];
    const void* lb     = p[4];
    const void* dw     = p[5];
    const void* dbm    = p[6];
    const void* pw     = p[7];
    const void* pbm    = p[8];

    float* w = (float*)d_ws;
    unsigned int* bar  = (unsigned int*)(w + OFF_BAR);
    int*          flag = (int*)bar + 400;   // outside zeroed [0,320) range

    detect_kernel<<<1, 256, 0, stream>>>((const unsigned short*)emb, flag);

    prep_kernel<<<(PREP_TOTAL + 255) / 256, 256, 0, stream>>>(
        lk, lb, dw, dbm, pw, pbm, flag, w);

    xproj_kernel<<<dim3(64, 256), 256, 0, stream>>>(X, emb, flag,
                                                    w + OFF_WFX, w + OFF_BIAS,
                                                    w + OFF_XPROJ);

    lstm_persistent<<<NB, 512, 0, stream>>>(w + OFF_HA, w + OFF_HB,
                                            w + OFF_CT, w + OFF_FH,
                                            w + OFF_WR, w + OFF_XPROJ,
                                            seqlen, bar);

    dense_kernel<<<32, 256, 0, stream>>>(w + OFF_FH, w + OFF_WD,
                                         w + OFF_DB, w + OFF_DEN);
    logits_kernel<<<1, 128, 0, stream>>>(w + OFF_DEN, w + OFF_WP,
                                         w + OFF_PB, flag, d_out);
}